// Round 7
// baseline (90.165 us; speedup 1.0000x reference)
//
#include <hip/hip_runtime.h>

// AttEncoder fused: per-channel conv1d encoder + channel attention (C=4).
// Key identity: w[b,i,j,t] = x_i(t)^T M_ij x_j(t), M_ij precomputed from W.
// Only the v-conv is done at full N=512; q/k convs are folded into M (16x16).
//
// R2: FC 64->16, grid 512->2048.  87->65 us.
// R3 FAILED: __launch_bounds__(256,1) -> 1 block/CU, no hiding. 88 us.
//     (NT stores were confounded into this round -- never fairly tested.)
// R4: (256,4) VGPR cap 128 + A[b][t][i][j] float4. 60 us.
// R5: 1024-thread blocks (4 KB store runs). 58 us -> run-length theory dead.
// R6: W staged in LDS. 61 us -> vmcnt-queue theory dead; ds_read issue cost
//     made it worse. Reverted.
// Invariants so far: k2 ~50 us / ~2.5 TB/s write BW across TLP, VGPR, run
//     length, W path. VALU issue only ~9 us. Fill kernel: 6.9 TB/s with MORE
//     streams -> DRAM-row theories dead. Remaining delta vs fill: fill uses
//     streaming stores; ours write-allocate 131 MB through 32 MB L2
//     (allocate/evict/writeback churn competing with x/A reads).
// R7: clean single-variable test: R5 structure + nontemporal stores on out.

#define BB 4
#define CC 4
#define LL 32000
#define KK 16
#define ST 8
#define NN 512
#define TT 3999      // (LL-KK)/ST + 1
#define F3 1536
#define FC 32        // f-chunk per block in k2

// ---------------- k0: M[i][j][k][k2] = sum_f Wq[i,f,k] * Wk[j,f,k2] ----------
// Wq[c,f,k] = W[(c*F3 + NN  + f)*KK + k]
// Wk[c,f,k] = W[(c*F3 + 0   + f)*KK + k]
__global__ __launch_bounds__(256) void k0_M(const float* __restrict__ W,
                                            float* __restrict__ M) {
  const int i = blockIdx.x >> 2, j = blockIdx.x & 3;
  __shared__ float wq[NN * KK];   // 32 KB
  __shared__ float wk[NN * KK];   // 32 KB
  const int baseq = (i * F3 + NN) * KK;
  const int basek = (j * F3) * KK;
  for (int idx = threadIdx.x; idx < NN * KK; idx += 256) {
    wq[idx] = W[baseq + idx];
    wk[idx] = W[basek + idx];
  }
  __syncthreads();
  const int k = threadIdx.x >> 4, k2 = threadIdx.x & 15;
  float acc = 0.f;
  for (int f = 0; f < NN; ++f)
    acc = fmaf(wq[f * KK + k], wk[f * KK + k2], acc);
  M[((i * 4 + j) * 16 + k) * 16 + k2] = acc;
}

// ---------------- k1: A[b][t][i][j] = 0.5*(softmax_j(w) + delta_ij) ---------
template <int I>
__device__ __forceinline__ void k1_row(const float xr[4][16],
                                       const float* __restrict__ M,
                                       float* __restrict__ A, int bb, int t) {
  float w[4];
#pragma unroll
  for (int j = 0; j < 4; ++j) {
    const float* Mp = M + (I * 4 + j) * 256;
    float acc = 0.f;
#pragma unroll
    for (int k = 0; k < 16; ++k) {
      float y = 0.f;
#pragma unroll
      for (int k2 = 0; k2 < 16; ++k2)
        y = fmaf(Mp[k * 16 + k2], xr[j][k2], y);
      acc = fmaf(xr[I][k], y, acc);
    }
    w[j] = acc;
  }
  const float m = fmaxf(fmaxf(w[0], w[1]), fmaxf(w[2], w[3]));
  const float e0 = __expf(w[0] - m), e1 = __expf(w[1] - m);
  const float e2 = __expf(w[2] - m), e3 = __expf(w[3] - m);
  const float inv = 0.5f / (e0 + e1 + e2 + e3);
  float4 av;
  av.x = e0 * inv;
  av.y = e1 * inv;
  av.z = e2 * inv;
  av.w = e3 * inv;
  if (I == 0) av.x += 0.5f;
  if (I == 1) av.y += 0.5f;
  if (I == 2) av.z += 0.5f;
  if (I == 3) av.w += 0.5f;
  // A[b][t][i][j], one float4 per (b,t,i)
  *reinterpret_cast<float4*>(A + ((bb * TT + t) * 4 + I) * 4) = av;
}

// block = 256 threads = 4 waves; each wave handles one query row i for the
// same 64 t values (uniform branch per wave, no divergence).
__global__ __launch_bounds__(256, 4) void k1_A(const float* __restrict__ x,
                                               const float* __restrict__ M,
                                               float* __restrict__ A) {
  const int bb = blockIdx.y;
  const int lane = threadIdx.x & 63;
  const int wv = threadIdx.x >> 6;
  const int t = blockIdx.x * 64 + lane;
  if (t >= TT) return;
  float xr[4][16];
#pragma unroll
  for (int c = 0; c < 4; ++c) {
    const float* xp = x + (bb * CC + c) * LL + t * ST;
#pragma unroll
    for (int k4 = 0; k4 < 16; k4 += 4) {
      const float4 v4 = *reinterpret_cast<const float4*>(xp + k4);
      xr[c][k4 + 0] = v4.x;
      xr[c][k4 + 1] = v4.y;
      xr[c][k4 + 2] = v4.z;
      xr[c][k4 + 3] = v4.w;
    }
  }
  if (wv == 0)      k1_row<0>(xr, M, A, bb, t);
  else if (wv == 1) k1_row<1>(xr, M, A, bb, t);
  else if (wv == 2) k1_row<2>(xr, M, A, bb, t);
  else              k1_row<3>(xr, M, A, bb, t);
}

// ---------------- k2: v-conv + mix + store ----------------------------------
// out[b,i,f,t] = sum_j A[b,t,i,j] * v[b,j,f,t],  v[c,f,t] = Wv[c,f,:] . x_c(t)
// Wv[c,f,k] = W[(c*F3 + 2*NN + f)*KK + k]   (wave-uniform index -> s_load)
// R7: nontemporal stores -- out is write-once, never re-read; bypass L2 so
// 131 MB of streaming writes stop churning the 32 MB L2.
__global__ __launch_bounds__(1024, 4) void k2_out(const float* __restrict__ x,
                                                  const float* __restrict__ W,
                                                  const float* __restrict__ A,
                                                  float* __restrict__ out) {
  const int bb = blockIdx.x >> 2;
  const int t = (blockIdx.x & 3) * 1024 + (int)threadIdx.x;
  const int f0 = blockIdx.y * FC;
  if (t >= TT) return;
  float xr[4][16];
#pragma unroll
  for (int c = 0; c < 4; ++c) {
    const float* xp = x + (bb * CC + c) * LL + t * ST;
#pragma unroll
    for (int k4 = 0; k4 < 16; k4 += 4) {
      const float4 v4 = *reinterpret_cast<const float4*>(xp + k4);
      xr[c][k4 + 0] = v4.x;
      xr[c][k4 + 1] = v4.y;
      xr[c][k4 + 2] = v4.z;
      xr[c][k4 + 3] = v4.w;
    }
  }
  float4 a[4];
  {
    const float4* ap = reinterpret_cast<const float4*>(A + (bb * TT + t) * 16);
#pragma unroll
    for (int i = 0; i < 4; ++i) a[i] = ap[i];
  }

#pragma unroll 2
  for (int f = 0; f < FC; ++f) {
    const int fg = f0 + f;
    const float* w0 = W + (0 * F3 + 2 * NN + fg) * KK;
    const float* w1 = W + (1 * F3 + 2 * NN + fg) * KK;
    const float* w2 = W + (2 * F3 + 2 * NN + fg) * KK;
    const float* w3 = W + (3 * F3 + 2 * NN + fg) * KK;
    float v0 = 0.f, v1 = 0.f, v2 = 0.f, v3 = 0.f;
#pragma unroll
    for (int k = 0; k < 16; ++k) {
      v0 = fmaf(w0[k], xr[0][k], v0);
      v1 = fmaf(w1[k], xr[1][k], v1);
      v2 = fmaf(w2[k], xr[2][k], v2);
      v3 = fmaf(w3[k], xr[3][k], v3);
    }
#pragma unroll
    for (int i = 0; i < 4; ++i) {
      const float o =
          fmaf(a[i].w, v3, fmaf(a[i].z, v2, fmaf(a[i].y, v1, a[i].x * v0)));
      __builtin_nontemporal_store(o, &out[((bb * 4 + i) * NN + fg) * TT + t]);
    }
  }
}

extern "C" void kernel_launch(void* const* d_in, const int* in_sizes, int n_in,
                              void* d_out, int out_size, void* d_ws,
                              size_t ws_size, hipStream_t stream) {
  const float* x = (const float*)d_in[0];   // [B, C, L] fp32
  const float* W = (const float*)d_in[1];   // [C, F3, 1, K] fp32
  float* out = (float*)d_out;               // [B, C, N, T] fp32
  float* Mws = (float*)d_ws;                // 4096 floats
  float* Aws = Mws + 4 * 4 * 16 * 16;       // B*T*4*4 floats (~1 MB)

  hipLaunchKernelGGL(k0_M, dim3(16), dim3(256), 0, stream, W, Mws);
  hipLaunchKernelGGL(k1_A, dim3(63, BB), dim3(256), 0, stream, x, Mws, Aws);
  // 16 blocks.x = 4 b * 4 t-tiles (1024 t each); 16 blocks.y = 512/FC f-tiles
  hipLaunchKernelGGL(k2_out, dim3(16, 16), dim3(1024), 0, stream, x, W, Aws,
                     out);
}

// Round 8
// 74.955 us; speedup vs baseline: 1.2029x; 1.2029x over previous
//
#include <hip/hip_runtime.h>

// AttEncoder fused: per-channel conv1d encoder + channel attention (C=4).
// w[b,i,j,t] = x_i(t)^T M_ij x_j(t) with M precomputed (16x16 per (i,j));
// only the v-conv runs at full N=512.
//
// R2: more blocks (87->65). R3 FAILED launch_bounds(256,1). R4: VGPR 128,
// A[b][t][i][j] (60). R5: 4KB store runs (58) - run-length theory dead.
// R6: W in LDS (61) - vmcnt-load theory inconclusive (ds_read issue cost).
// R7 FAILED: NT stores 58->90 -> store path is latency x depth limited;
//     L2-ack (not HBM-ack) is the normal drain; L2 churn theory dead.
// R8: width lever + clean vmcnt: wave=channel (W via s_load), x/A preloaded,
//     f-loop VMEM = stores ONLY; 2t/lane -> aligned float2 stores (512B/instr,
//     2x bytes-in-flight); v exchange via 4KB LDS dbuf with raw s_barrier +
//     lgkmcnt(0) only (stores never drained in-loop). Parity of row base =
//     fg&1 (TT odd) -> odd-f iters use shifted pairing, lane63 does edges.

#define BB 4
#define CC 4
#define LL 32000
#define KK 16
#define ST 8
#define NN 512
#define TT 3999      // (LL-KK)/ST + 1
#define F3 1536
#define FC 32        // f per block in k2
#define TTILE 128    // t per block in k2
#define NTT 32       // ceil(TT/TTILE)

// ---------------- k0: M[i][j][k][k2] = sum_f Wq[i,f,k] * Wk[j,f,k2] ----------
__global__ __launch_bounds__(256) void k0_M(const float* __restrict__ W,
                                            float* __restrict__ M) {
  const int i = blockIdx.x >> 2, j = blockIdx.x & 3;
  __shared__ float wq[NN * KK];
  __shared__ float wk[NN * KK];
  const int baseq = (i * F3 + NN) * KK;
  const int basek = (j * F3) * KK;
  for (int idx = threadIdx.x; idx < NN * KK; idx += 256) {
    wq[idx] = W[baseq + idx];
    wk[idx] = W[basek + idx];
  }
  __syncthreads();
  const int k = threadIdx.x >> 4, k2 = threadIdx.x & 15;
  float acc = 0.f;
  for (int f = 0; f < NN; ++f)
    acc = fmaf(wq[f * KK + k], wk[f * KK + k2], acc);
  M[((i * 4 + j) * 16 + k) * 16 + k2] = acc;
}

// ---------------- k1: A[b][t][i][j] = 0.5*(softmax_j(w) + delta_ij) ---------
template <int I>
__device__ __forceinline__ void k1_row(const float xr[4][16],
                                       const float* __restrict__ M,
                                       float* __restrict__ A, int bb, int t) {
  float w[4];
#pragma unroll
  for (int j = 0; j < 4; ++j) {
    const float* Mp = M + (I * 4 + j) * 256;
    float acc = 0.f;
#pragma unroll
    for (int k = 0; k < 16; ++k) {
      float y = 0.f;
#pragma unroll
      for (int k2 = 0; k2 < 16; ++k2)
        y = fmaf(Mp[k * 16 + k2], xr[j][k2], y);
      acc = fmaf(xr[I][k], y, acc);
    }
    w[j] = acc;
  }
  const float m = fmaxf(fmaxf(w[0], w[1]), fmaxf(w[2], w[3]));
  const float e0 = __expf(w[0] - m), e1 = __expf(w[1] - m);
  const float e2 = __expf(w[2] - m), e3 = __expf(w[3] - m);
  const float inv = 0.5f / (e0 + e1 + e2 + e3);
  float4 av;
  av.x = e0 * inv;
  av.y = e1 * inv;
  av.z = e2 * inv;
  av.w = e3 * inv;
  if (I == 0) av.x += 0.5f;
  if (I == 1) av.y += 0.5f;
  if (I == 2) av.z += 0.5f;
  if (I == 3) av.w += 0.5f;
  *reinterpret_cast<float4*>(A + ((bb * TT + t) * 4 + I) * 4) = av;
}

__global__ __launch_bounds__(256, 4) void k1_A(const float* __restrict__ x,
                                               const float* __restrict__ M,
                                               float* __restrict__ A) {
  const int bb = blockIdx.y;
  const int lane = threadIdx.x & 63;
  const int wv = threadIdx.x >> 6;
  const int t = blockIdx.x * 64 + lane;
  if (t >= TT) return;
  float xr[4][16];
#pragma unroll
  for (int c = 0; c < 4; ++c) {
    const float* xp = x + (bb * CC + c) * LL + t * ST;
#pragma unroll
    for (int k4 = 0; k4 < 16; k4 += 4) {
      const float4 v4 = *reinterpret_cast<const float4*>(xp + k4);
      xr[c][k4 + 0] = v4.x;
      xr[c][k4 + 1] = v4.y;
      xr[c][k4 + 2] = v4.z;
      xr[c][k4 + 3] = v4.w;
    }
  }
  if (wv == 0)      k1_row<0>(xr, M, A, bb, t);
  else if (wv == 1) k1_row<1>(xr, M, A, bb, t);
  else if (wv == 2) k1_row<2>(xr, M, A, bb, t);
  else              k1_row<3>(xr, M, A, bb, t);
}

// ---------------- k2: v-conv + mix + wide store ------------------------------
// wave = channel c; lane owns t-pair (t0b+2l, t0b+2l+1) for conv (v) and a
// parity-shifted pair for mix/store so float2 stores are 8B-aligned.
__global__ __launch_bounds__(256, 8) void k2_out(const float* __restrict__ x,
                                                 const float* __restrict__ W,
                                                 const float* __restrict__ A,
                                                 float* __restrict__ out) {
  __shared__ float buf[2][4][TTILE];   // [dbuf][c][t_local], 4 KB
  const int tid = (int)threadIdx.x;
  const int ln = tid & 63;
  const int cc = __builtin_amdgcn_readfirstlane(tid >> 6);  // wave-uniform c
  const int bb = blockIdx.x >> 5;
  const int t0b = (blockIdx.x & 31) * TTILE;
  const int f0 = blockIdx.y * FC;

  // ---- x preload: pair window [8t, 8t+24), tail-clamped ----
  const int bt = t0b + 2 * ln;
  const int tb0 = min(bt, TT - 1);
  const int tb1 = min(bt + 1, TT - 1);
  const float* xc = x + (bb * CC + cc) * LL;
  float xa[16], xb[8];
  {
    const float4* p0 = reinterpret_cast<const float4*>(xc + 8 * tb0);
#pragma unroll
    for (int q = 0; q < 4; ++q) {
      const float4 v4 = p0[q];
      xa[q * 4 + 0] = v4.x;
      xa[q * 4 + 1] = v4.y;
      xa[q * 4 + 2] = v4.z;
      xa[q * 4 + 3] = v4.w;
    }
    const float4* p1 = reinterpret_cast<const float4*>(xc + 8 * tb1 + 8);
#pragma unroll
    for (int q = 0; q < 2; ++q) {
      const float4 v4 = p1[q];
      xb[q * 4 + 0] = v4.x;
      xb[q * 4 + 1] = v4.y;
      xb[q * 4 + 2] = v4.z;
      xb[q * 4 + 3] = v4.w;
    }
  }

  // ---- A preload (t_locals 2l, 2l+1, 2l+2, and 0 for lane63-odd) ----
  const float4* A4 = reinterpret_cast<const float4*>(A);
  const float4 aA = A4[(bb * TT + tb0) * 4 + cc];
  const float4 aB = A4[(bb * TT + tb1) * 4 + cc];
  const float4 aC = A4[(bb * TT + min(bt + 2, TT - 1)) * 4 + cc];
  const float4 aZ = A4[(bb * TT + t0b) * 4 + cc];

  for (int f = 0; f < FC; ++f) {
    const int fg = f0 + f;
    // W row: wave-uniform -> s_load; lgkmcnt only.
    const float* wr = W + (cc * F3 + 2 * NN + fg) * KK;
    float v0 = 0.f, v1 = 0.f;
#pragma unroll
    for (int k = 0; k < 16; ++k) v0 = fmaf(wr[k], xa[k], v0);
#pragma unroll
    for (int k = 0; k < 8; ++k) v1 = fmaf(wr[k], xa[k + 8], v1);
#pragma unroll
    for (int k = 8; k < 16; ++k) v1 = fmaf(wr[k], xb[k - 8], v1);

    const int p = f & 1;
    *reinterpret_cast<float2*>(&buf[p][cc][2 * ln]) = make_float2(v0, v1);
    // Drain LDS (and s_loads) only -- stores stay in flight across barrier.
    asm volatile("s_waitcnt lgkmcnt(0)" ::: "memory");
    __builtin_amdgcn_s_barrier();

    const int par = fg & 1;
    float o0 = 0.f, o1 = 0.f;
    int r0;
    if (!par) {
      r0 = 2 * ln;  // pair (2l, 2l+1); row base even -> aligned
      o0 = fmaf(aA.x, buf[p][0][r0], o0);
      o1 = fmaf(aB.x, buf[p][0][r0 + 1], o1);
      o0 = fmaf(aA.y, buf[p][1][r0], o0);
      o1 = fmaf(aB.y, buf[p][1][r0 + 1], o1);
      o0 = fmaf(aA.z, buf[p][2][r0], o0);
      o1 = fmaf(aB.z, buf[p][2][r0 + 1], o1);
      o0 = fmaf(aA.w, buf[p][3][r0], o0);
      o1 = fmaf(aB.w, buf[p][3][r0 + 1], o1);
    } else if (ln < 63) {
      r0 = 2 * ln + 1;  // shifted pair (2l+1, 2l+2); odd row base -> aligned
      o0 = fmaf(aB.x, buf[p][0][r0], o0);
      o1 = fmaf(aC.x, buf[p][0][r0 + 1], o1);
      o0 = fmaf(aB.y, buf[p][1][r0], o0);
      o1 = fmaf(aC.y, buf[p][1][r0 + 1], o1);
      o0 = fmaf(aB.z, buf[p][2][r0], o0);
      o1 = fmaf(aC.z, buf[p][2][r0 + 1], o1);
      o0 = fmaf(aB.w, buf[p][3][r0], o0);
      o1 = fmaf(aC.w, buf[p][3][r0 + 1], o1);
    } else {
      r0 = 127;  // edges: t_local 127 (o0) and 0 (o1)
      o0 = fmaf(aB.x, buf[p][0][127], o0);
      o1 = fmaf(aZ.x, buf[p][0][0], o1);
      o0 = fmaf(aB.y, buf[p][1][127], o0);
      o1 = fmaf(aZ.y, buf[p][1][0], o1);
      o0 = fmaf(aB.z, buf[p][2][127], o0);
      o1 = fmaf(aZ.z, buf[p][2][0], o1);
      o0 = fmaf(aB.w, buf[p][3][127], o0);
      o1 = fmaf(aZ.w, buf[p][3][0], o1);
    }

    const int orow = ((bb * 4 + cc) * NN + fg) * TT;
    const int gt0 = t0b + r0;
    if (par && ln == 63) {
      if (gt0 < TT) out[orow + gt0] = o0;  // t_local 127
      out[orow + t0b] = o1;                // t_local 0 (always < TT)
    } else if (gt0 + 1 < TT) {
      *reinterpret_cast<float2*>(out + orow + gt0) = make_float2(o0, o1);
    } else if (gt0 < TT) {
      out[orow + gt0] = o0;
    }
  }
}

extern "C" void kernel_launch(void* const* d_in, const int* in_sizes, int n_in,
                              void* d_out, int out_size, void* d_ws,
                              size_t ws_size, hipStream_t stream) {
  const float* x = (const float*)d_in[0];   // [B, C, L] fp32
  const float* W = (const float*)d_in[1];   // [C, F3, 1, K] fp32
  float* out = (float*)d_out;               // [B, C, N, T] fp32
  float* Mws = (float*)d_ws;                // 4096 floats
  float* Aws = Mws + 4 * 4 * 16 * 16;       // B*T*4*4 floats (~1 MB)

  hipLaunchKernelGGL(k0_M, dim3(16), dim3(256), 0, stream, W, Mws);
  hipLaunchKernelGGL(k1_A, dim3(63, BB), dim3(256), 0, stream, x, Mws, Aws);
  // grid: (4 b x 32 t-tiles, 16 f-tiles), 256 thr, 8 blocks/CU -> 1 round
  hipLaunchKernelGGL(k2_out, dim3(BB * NTT, NN / FC), dim3(256), 0, stream, x,
                     W, Aws, out);
}

// Round 9
// 65.159 us; speedup vs baseline: 1.3838x; 1.1503x over previous
//
#include <hip/hip_runtime.h>

// AttEncoder fused: per-channel conv1d encoder + channel attention (C=4).
// w[b,i,j,t] = x_i(t)^T M_ij x_j(t) with M precomputed (16x16 per (i,j));
// only the v-conv runs at full N=512.
//
// R2: more blocks (87->65). R3 FAILED lb(256,1). R4: VGPR 128 + A[b][t][i][j]
// (60). R5: 4KB store runs (58) - run-length theory dead. R6: W in LDS (61).
// R7 FAILED: NT stores 58->90 (higher ack latency -> depth*latency worse).
// R8 FAILED: float2+per-f barriers (75): same bytes-in-flight, added sync.
// R9: store-depth lever done right: conv/mix identical to R5 (t-per-lane,
//     x/A in regs, W s_load, zero in-loop vector loads); buffer o over 4-f
//     groups; intra-wave LDS transpose (same-wave ds ops are in-order -> NO
//     barriers) -> each lane stores one float4 (4 consecutive t) per i ->
//     4 distinct dwordx4 stores in flight (4 KB/wave vs 1 KB). Stores are
//     4B-aligned (TT odd); gfx950 unaligned VMEM mode handles dwordx4.

#define BB 4
#define CC 4
#define LL 32000
#define KK 16
#define ST 8
#define NN 512
#define TT 3999      // (LL-KK)/ST + 1
#define F3 1536
#define FC 32        // f per block in k2

// ---------------- k0: M[i][j][k][k2] = sum_f Wq[i,f,k] * Wk[j,f,k2] ----------
__global__ __launch_bounds__(256) void k0_M(const float* __restrict__ W,
                                            float* __restrict__ M) {
  const int i = blockIdx.x >> 2, j = blockIdx.x & 3;
  __shared__ float wq[NN * KK];
  __shared__ float wk[NN * KK];
  const int baseq = (i * F3 + NN) * KK;
  const int basek = (j * F3) * KK;
  for (int idx = threadIdx.x; idx < NN * KK; idx += 256) {
    wq[idx] = W[baseq + idx];
    wk[idx] = W[basek + idx];
  }
  __syncthreads();
  const int k = threadIdx.x >> 4, k2 = threadIdx.x & 15;
  float acc = 0.f;
  for (int f = 0; f < NN; ++f)
    acc = fmaf(wq[f * KK + k], wk[f * KK + k2], acc);
  M[((i * 4 + j) * 16 + k) * 16 + k2] = acc;
}

// ---------------- k1: A[b][t][i][j] = 0.5*(softmax_j(w) + delta_ij) ---------
template <int I>
__device__ __forceinline__ void k1_row(const float xr[4][16],
                                       const float* __restrict__ M,
                                       float* __restrict__ A, int bb, int t) {
  float w[4];
#pragma unroll
  for (int j = 0; j < 4; ++j) {
    const float* Mp = M + (I * 4 + j) * 256;
    float acc = 0.f;
#pragma unroll
    for (int k = 0; k < 16; ++k) {
      float y = 0.f;
#pragma unroll
      for (int k2 = 0; k2 < 16; ++k2)
        y = fmaf(Mp[k * 16 + k2], xr[j][k2], y);
      acc = fmaf(xr[I][k], y, acc);
    }
    w[j] = acc;
  }
  const float m = fmaxf(fmaxf(w[0], w[1]), fmaxf(w[2], w[3]));
  const float e0 = __expf(w[0] - m), e1 = __expf(w[1] - m);
  const float e2 = __expf(w[2] - m), e3 = __expf(w[3] - m);
  const float inv = 0.5f / (e0 + e1 + e2 + e3);
  float4 av;
  av.x = e0 * inv;
  av.y = e1 * inv;
  av.z = e2 * inv;
  av.w = e3 * inv;
  if (I == 0) av.x += 0.5f;
  if (I == 1) av.y += 0.5f;
  if (I == 2) av.z += 0.5f;
  if (I == 3) av.w += 0.5f;
  *reinterpret_cast<float4*>(A + ((bb * TT + t) * 4 + I) * 4) = av;
}

__global__ __launch_bounds__(256, 4) void k1_A(const float* __restrict__ x,
                                               const float* __restrict__ M,
                                               float* __restrict__ A) {
  const int bb = blockIdx.y;
  const int lane = threadIdx.x & 63;
  const int wv = threadIdx.x >> 6;
  const int t = blockIdx.x * 64 + lane;
  if (t >= TT) return;
  float xr[4][16];
#pragma unroll
  for (int c = 0; c < 4; ++c) {
    const float* xp = x + (bb * CC + c) * LL + t * ST;
#pragma unroll
    for (int k4 = 0; k4 < 16; k4 += 4) {
      const float4 v4 = *reinterpret_cast<const float4*>(xp + k4);
      xr[c][k4 + 0] = v4.x;
      xr[c][k4 + 1] = v4.y;
      xr[c][k4 + 2] = v4.z;
      xr[c][k4 + 3] = v4.w;
    }
  }
  if (wv == 0)      k1_row<0>(xr, M, A, bb, t);
  else if (wv == 1) k1_row<1>(xr, M, A, bb, t);
  else if (wv == 2) k1_row<2>(xr, M, A, bb, t);
  else              k1_row<3>(xr, M, A, bb, t);
}

// ---------------- k2: v-conv + mix + transposed x4 store ---------------------
// Per wave (64 t): conv+mix per lane-t as R5; every 4 f, transpose the 64x4
// o-block through LDS (intra-wave, in-order, barrier-free) so each lane holds
// 4 consecutive t of ONE f-row -> one dwordx4 store per i (4 in flight).
__global__ __launch_bounds__(256, 3) void k2_out(const float* __restrict__ x,
                                                 const float* __restrict__ W,
                                                 const float* __restrict__ A,
                                                 float* __restrict__ out) {
  __shared__ float tbuf[4][256];   // [wave][f_sub*64 + lane], 4 KB
  const int tid = (int)threadIdx.x;
  const int ln = tid & 63;
  const int wv = tid >> 6;
  const int bb = blockIdx.x >> 4;
  const int t0w = (blockIdx.x & 15) * 256 + wv * 64;  // wave's t base
  const int f0 = blockIdx.y * FC;
  const int t = t0w + ln;
  const int tcl = min(t, TT - 1);   // clamp for preloads; OOB lanes never store

  // ---- x preload: xr[c][16], window [8t, 8t+16) ----
  float xr[4][16];
#pragma unroll
  for (int c = 0; c < 4; ++c) {
    const float* xp = x + (bb * CC + c) * LL + tcl * ST;
#pragma unroll
    for (int k4 = 0; k4 < 16; k4 += 4) {
      const float4 v4 = *reinterpret_cast<const float4*>(xp + k4);
      xr[c][k4 + 0] = v4.x;
      xr[c][k4 + 1] = v4.y;
      xr[c][k4 + 2] = v4.z;
      xr[c][k4 + 3] = v4.w;
    }
  }
  // ---- A preload: a[i] = A[b][t][i][0..3] ----
  float4 a[4];
  {
    const float4* ap =
        reinterpret_cast<const float4*>(A + (bb * TT + tcl) * 16);
#pragma unroll
    for (int i = 0; i < 4; ++i) a[i] = ap[i];
  }

  const int fprow = ln >> 4;        // f-sub row this lane stores
  const int tq = (ln & 15) * 4;     // t-offset within wave segment
  const int tg = t0w + tq;          // global t of this lane's float4

  for (int g = 0; g < FC / 4; ++g) {
    // ---- compute o[i][fj] for 4 f's at own t ----
    float o[4][4];
#pragma unroll
    for (int fj = 0; fj < 4; ++fj) {
      const int fg = f0 + g * 4 + fj;
      const float* w0 = W + (0 * F3 + 2 * NN + fg) * KK;
      const float* w1 = W + (1 * F3 + 2 * NN + fg) * KK;
      const float* w2 = W + (2 * F3 + 2 * NN + fg) * KK;
      const float* w3 = W + (3 * F3 + 2 * NN + fg) * KK;
      float v0 = 0.f, v1 = 0.f, v2 = 0.f, v3 = 0.f;
#pragma unroll
      for (int k = 0; k < 16; ++k) {
        v0 = fmaf(w0[k], xr[0][k], v0);
        v1 = fmaf(w1[k], xr[1][k], v1);
        v2 = fmaf(w2[k], xr[2][k], v2);
        v3 = fmaf(w3[k], xr[3][k], v3);
      }
#pragma unroll
      for (int i = 0; i < 4; ++i)
        o[i][fj] = fmaf(a[i].w, v3,
                        fmaf(a[i].z, v2, fmaf(a[i].y, v1, a[i].x * v0)));
    }

    // ---- intra-wave transpose (in-order LDS, no barrier) ----
    float4 tr[4];
#pragma unroll
    for (int i = 0; i < 4; ++i) {
      tbuf[wv][0 * 64 + ln] = o[i][0];
      tbuf[wv][1 * 64 + ln] = o[i][1];
      tbuf[wv][2 * 64 + ln] = o[i][2];
      tbuf[wv][3 * 64 + ln] = o[i][3];
      tr[i] = *reinterpret_cast<const float4*>(&tbuf[wv][fprow * 64 + tq]);
    }

    // ---- 4 wide stores, distinct source regs (4 KB in flight) ----
#pragma unroll
    for (int i = 0; i < 4; ++i) {
      const int row = ((bb * 4 + i) * NN + f0 + g * 4 + fprow);
      float* op = out + (size_t)row * TT + tg;
      if (tg + 3 < TT) {
        *reinterpret_cast<float4*>(op) = tr[i];
      } else {
        if (tg + 0 < TT) op[0] = tr[i].x;
        if (tg + 1 < TT) op[1] = tr[i].y;
        if (tg + 2 < TT) op[2] = tr[i].z;
      }
    }
  }
}

extern "C" void kernel_launch(void* const* d_in, const int* in_sizes, int n_in,
                              void* d_out, int out_size, void* d_ws,
                              size_t ws_size, hipStream_t stream) {
  const float* x = (const float*)d_in[0];   // [B, C, L] fp32
  const float* W = (const float*)d_in[1];   // [C, F3, 1, K] fp32
  float* out = (float*)d_out;               // [B, C, N, T] fp32
  float* Mws = (float*)d_ws;                // 4096 floats
  float* Aws = Mws + 4 * 4 * 16 * 16;       // B*T*4*4 floats (~1 MB)

  hipLaunchKernelGGL(k0_M, dim3(16), dim3(256), 0, stream, W, Mws);
  hipLaunchKernelGGL(k1_A, dim3(63, BB), dim3(256), 0, stream, x, Mws, Aws);
  // grid: (4 b x 16 t-tiles of 256) x (16 f-tiles of 32); 256 thr, 4 waves
  hipLaunchKernelGGL(k2_out, dim3(BB * 16, NN / FC), dim3(256), 0, stream, x,
                     W, Aws, out);
}